// Round 2
// baseline (11461.533 us; speedup 1.0000x reference)
//
#include <hip/hip_runtime.h>
#include <math.h>

#define NB 4
#define L0 8192
#define CR 32
#define CD 32
#define CS 512
#define CE 256
#define NV 256
#define OUT_T 5632
#define XSTRIDE 8192

// ---------------- Kernel A: embedding + causal pre-conv (k=2) ----------------
__global__ __launch_bounds__(256) void k_pre(const int* __restrict__ tokens,
                                             const float* __restrict__ emb,
                                             const float* __restrict__ pw,
                                             float* __restrict__ x)
{
    int idx = blockIdx.x * 256 + threadIdx.x;
    int t = idx & (L0 - 1);
    int o = (idx >> 13) & 31;
    int b = idx >> 18;
    const int* tb = tokens + b * L0;
    int tok = tb[t];
    const float* e1 = emb + tok * CR;
    const float* w = pw + o * CR * 2;
    float acc = 0.f;
    if (t > 0) {
        const float* e0 = emb + tb[t - 1] * CR;
#pragma unroll
        for (int i = 0; i < CR; ++i)
            acc += w[i * 2] * e0[i] + w[i * 2 + 1] * e1[i];
    } else {
#pragma unroll
        for (int i = 0; i < CR; ++i)
            acc += w[i * 2 + 1] * e1[i];
    }
    x[(b * CR + o) * XSTRIDE + t] = acc;
}

// ---------------- Kernel B: one WaveNet layer (unfolded coords) ----------------
// z[t] = tanh(Wf0 x[t] + Wf1 x[t+d]) * sig(Wg0 x[t] + Wg1 x[t+d])
// x_out[t] = Wr z[t] + x[t+d];  skip[o] (+)= Ws z[o + skipOff]
// xin(t) = (t < P) ? 0 : x_in[t - P]   (front zero-padding)
__global__ __launch_bounds__(256) void k_layer(
    const float* __restrict__ x_in, float* __restrict__ x_out,
    float* __restrict__ skip,
    const float* __restrict__ fw, const float* __restrict__ gw,
    const float* __restrict__ rw, const float* __restrict__ sw,
    int T_out, int d, int P, int skipOff, int accum)
{
    __shared__ float As[32][65];
    __shared__ float Bs[32][65];
    __shared__ float Zs[32][65];
    const int tid = threadIdx.x;
    const int t0 = blockIdx.x * 64;
    const int b = blockIdx.y;
    const float* xb = x_in + b * CR * XSTRIDE;

    // ---- load x tiles (A = xin(t), B = xin(t+d)) ----
    {
        int ch = tid >> 3;
        int j0 = (tid & 7) * 8;
        const float* row = xb + ch * XSTRIDE;
#pragma unroll
        for (int k = 0; k < 8; ++k) {
            int t = t0 + j0 + k;
            float a = 0.f, bb = 0.f;
            if (t < T_out) {
                if (t >= P) a = row[t - P];
                bb = row[t + d - P];   // always >= 0 since d > P
            }
            As[ch][j0 + k] = a;
            Bs[ch][j0 + k] = bb;
        }
    }
    __syncthreads();

    // ---- gated activation z ----
    {
        int c = tid & 31;
        int j0 = (tid >> 5) * 8;
        const float* wf = fw + c * CR * 2;
        const float* wg = gw + c * CR * 2;
        float af[8] = {0, 0, 0, 0, 0, 0, 0, 0};
        float ag[8] = {0, 0, 0, 0, 0, 0, 0, 0};
#pragma unroll
        for (int i = 0; i < CR; ++i) {
            float f0 = wf[i * 2], f1 = wf[i * 2 + 1];
            float g0 = wg[i * 2], g1 = wg[i * 2 + 1];
#pragma unroll
            for (int k = 0; k < 8; ++k) {
                float a = As[i][j0 + k];
                float bb = Bs[i][j0 + k];
                af[k] += f0 * a + f1 * bb;
                ag[k] += g0 * a + g1 * bb;
            }
        }
#pragma unroll
        for (int k = 0; k < 8; ++k) {
            float z = tanhf(af[k]) * (1.f / (1.f + expf(-ag[k])));
            Zs[c][j0 + k] = z;
        }
    }
    __syncthreads();

    // ---- residual: x_out = Wr z + xin(t+d) ----
    {
        int ch = tid >> 3;
        int j0 = (tid & 7) * 8;
        const float* wr = rw + ch * CD;
        float* orow = x_out + (b * CR + ch) * XSTRIDE;
#pragma unroll
        for (int k = 0; k < 8; ++k) {
            int t = t0 + j0 + k;
            if (t < T_out) {
                float acc = Bs[ch][j0 + k];
#pragma unroll
                for (int i = 0; i < CD; ++i)
                    acc += wr[i] * Zs[i][j0 + k];
                orow[t] = acc;
            }
        }
    }

    // ---- skip contribution (only tiles overlapping final 5632 outputs) ----
    if (t0 + 63 >= skipOff) {
        int tt = tid & 63;
        int cog = tid >> 6;           // wave-uniform
        int t = t0 + tt;
        bool valid = (t >= skipOff) && (t < T_out);
        int o = t - skipOff;
        float* sb = skip + (size_t)b * CS * OUT_T + o;
        for (int r = 0; r < 128; ++r) {
            int co = cog * 128 + r;
            const float* wsrow = sw + co * CD;
            float acc = 0.f;
#pragma unroll
            for (int i = 0; i < CD; ++i)
                acc += wsrow[i] * Zs[i][tt];
            if (valid) {
                float* p = sb + (size_t)co * OUT_T;
                if (accum) *p += acc; else *p = acc;
            }
        }
    }
}

// ---------------- Kernel C1: h1 = relu(W1 relu(skip) + b1) ----------------
__global__ __launch_bounds__(256) void k_post1(const float* __restrict__ skip,
                                               const float* __restrict__ w1,
                                               const float* __restrict__ b1,
                                               float* __restrict__ h1)
{
    int o = blockIdx.x * 64 + (threadIdx.x & 63);
    int e = blockIdx.y * 4 + (threadIdx.x >> 6);
    int b = blockIdx.z;
    const float* srow = skip + (size_t)b * CS * OUT_T + o;
    const float* wrow = w1 + e * CS;
    float acc = b1[e];
    for (int s = 0; s < CS; ++s) {
        float v = srow[(size_t)s * OUT_T];
        acc += wrow[s] * (v > 0.f ? v : 0.f);
    }
    h1[((size_t)b * CE + e) * OUT_T + o] = acc > 0.f ? acc : 0.f;
}

// ---------------- Kernel C2: out = W2 h1 + b2 ----------------
__global__ __launch_bounds__(256) void k_post2(const float* __restrict__ h1,
                                               const float* __restrict__ w2,
                                               const float* __restrict__ b2,
                                               float* __restrict__ out)
{
    int o = blockIdx.x * 64 + (threadIdx.x & 63);
    int v = blockIdx.y * 4 + (threadIdx.x >> 6);
    int b = blockIdx.z;
    const float* hrow = h1 + (size_t)b * CE * OUT_T + o;
    const float* wrow = w2 + v * CE;
    float acc = b2[v];
    for (int e = 0; e < CE; ++e)
        acc += wrow[e] * hrow[(size_t)e * OUT_T];
    out[((size_t)b * NV + v) * OUT_T + o] = acc;
}

extern "C" void kernel_launch(void* const* d_in, const int* in_sizes, int n_in,
                              void* d_out, int out_size, void* d_ws, size_t ws_size,
                              hipStream_t stream)
{
    const int*   tokens  = (const int*)d_in[0];
    const float* emb     = (const float*)d_in[1];
    const float* pre_w   = (const float*)d_in[2];
    const float* filt_w  = (const float*)d_in[3];
    const float* gate_w  = (const float*)d_in[4];
    const float* res_w   = (const float*)d_in[5];
    const float* skip_w  = (const float*)d_in[6];
    const float* post_w1 = (const float*)d_in[7];
    const float* post_b1 = (const float*)d_in[8];
    const float* post_w2 = (const float*)d_in[9];
    const float* post_b2 = (const float*)d_in[10];
    float* out = (float*)d_out;

    float* xA   = (float*)d_ws;
    float* xB   = xA + (size_t)NB * CR * XSTRIDE;           // 1 MiB floats each
    float* skip = xB + (size_t)NB * CR * XSTRIDE;
    float* h1   = skip + (size_t)NB * CS * OUT_T;

    k_pre<<<(NB * CR * L0) / 256, 256, 0, stream>>>(tokens, emb, pre_w, xA);

    // layer schedule (static, mirrors reference dilate() padding exactly)
    int T = L0;
    int init = 1;
    float* xin = xA;
    float* xout = xB;
    int li = 0;
    for (int blk = 0; blk < 5; ++blk) {
        int nw = 1;
        for (int j = 0; j < 10; ++j) {
            int d = nw;
            int P = 0;
            if (d > init) {
                int r = d / init;
                int l = T / init;          // T always divisible by init here
                int nl = ((l + r - 1) / r) * r;
                P = (nl - l) * init;
            }
            int T_in = T + P;
            int T_out = T_in - d;
            dim3 grid((T_out + 63) / 64, NB);
            k_layer<<<grid, 256, 0, stream>>>(
                xin, xout, skip,
                filt_w + (size_t)li * CD * CR * 2,
                gate_w + (size_t)li * CD * CR * 2,
                res_w + (size_t)li * CR * CD,
                skip_w + (size_t)li * CS * CD,
                T_out, d, P, T_out - OUT_T, li == 0 ? 0 : 1);
            float* tmp = xin; xin = xout; xout = tmp;
            T = T_out;
            init = d;
            nw <<= 1;
            ++li;
        }
    }

    dim3 g1(OUT_T / 64, CE / 4, NB);
    k_post1<<<g1, 256, 0, stream>>>(skip, post_w1, post_b1, h1);
    dim3 g2(OUT_T / 64, NV / 4, NB);
    k_post2<<<g2, 256, 0, stream>>>(h1, post_w2, post_b2, out);
}

// Round 3
// 1451.201 us; speedup vs baseline: 7.8980x; 7.8980x over previous
//
#include <hip/hip_runtime.h>
#include <math.h>

#define NB 4
#define L0 8192
#define CR 32
#define CD 32
#define CS 512
#define CE 256
#define NV 256
#define OUT_T 5632
#define XSTRIDE 8192
#define NL 50
#define KCAT 1600   // 50 * 32

typedef __attribute__((ext_vector_type(8))) short  short8;
typedef __attribute__((ext_vector_type(4))) float  f32x4;
typedef __attribute__((ext_vector_type(4))) float  f4;
typedef __attribute__((ext_vector_type(4))) unsigned short us4;

static __device__ __forceinline__ unsigned short f2bf(float f) {
    unsigned int u = __builtin_bit_cast(unsigned int, f);
    u = (u + 0x7FFFu + ((u >> 16) & 1u)) >> 16;
    return (unsigned short)u;
}

// ---------------- Kernel P: weight f32 -> bf16 prep ----------------
// wsb[co][l*32+c] = skip_w[l][co][c]; w1b, w2b direct convert.
__global__ __launch_bounds__(256) void k_prep(const float* __restrict__ sw,
                                              const float* __restrict__ w1,
                                              const float* __restrict__ w2,
                                              unsigned short* __restrict__ wsb,
                                              unsigned short* __restrict__ w1b,
                                              unsigned short* __restrict__ w2b)
{
    int idx = blockIdx.x * 256 + threadIdx.x;
    if (idx < NL * CS * CD) {
        int l = idx >> 14;            // / (512*32)
        int co = (idx >> 5) & 511;
        int c = idx & 31;
        wsb[co * KCAT + l * 32 + c] = f2bf(sw[idx]);
    } else if (idx < NL * CS * CD + CE * CS) {
        int e = idx - NL * CS * CD;
        w1b[e] = f2bf(w1[e]);
    } else {
        int e = idx - NL * CS * CD - CE * CS;
        w2b[e] = f2bf(w2[e]);
    }
}

// ---------------- Kernel A: embedding + causal pre-conv (k=2) ----------------
__global__ __launch_bounds__(256) void k_pre(const int* __restrict__ tokens,
                                             const float* __restrict__ emb,
                                             const float* __restrict__ pw,
                                             float* __restrict__ x)
{
    int idx = blockIdx.x * 256 + threadIdx.x;
    int t = idx & (L0 - 1);
    int o = (idx >> 13) & 31;
    int b = idx >> 18;
    const int* tb = tokens + b * L0;
    int tok = tb[t];
    const float* e1 = emb + tok * CR;
    const float* w = pw + o * CR * 2;
    float acc = 0.f;
    if (t > 0) {
        const float* e0 = emb + tb[t - 1] * CR;
#pragma unroll
        for (int i = 0; i < CR; ++i)
            acc += w[i * 2] * e0[i] + w[i * 2 + 1] * e1[i];
    } else {
#pragma unroll
        for (int i = 0; i < CR; ++i)
            acc += w[i * 2 + 1] * e1[i];
    }
    x[(b * CR + o) * XSTRIDE + t] = acc;
}

// ---------------- Kernel B: one WaveNet layer (no skip RMW) ----------------
// z[t] = tanh(Wf0 x[t] + Wf1 x[t+d]) * sig(Wg0 x[t] + Wg1 x[t+d])
// x_out[t] = Wr z[t] + x[t+d]
// Zt[b][t-skipOff][kOff + c] = bf16(z)   for t in [skipOff, T_out)
__global__ __launch_bounds__(256) void k_layer(
    const float* __restrict__ x_in, float* __restrict__ x_out,
    unsigned short* __restrict__ Zt,
    const float* __restrict__ fw, const float* __restrict__ gw,
    const float* __restrict__ rw,
    int T_out, int d, int P, int skipOff, int kOff)
{
    __shared__ float As[32][68];
    __shared__ float Bs[32][68];
    __shared__ float Zs[32][68];
    __shared__ unsigned short ZsT[64][32];
    __shared__ float wfT[64][33];
    __shared__ float wgT[64][33];
    __shared__ float rwT[32][33];
    const int tid = threadIdx.x;
    const int t0 = blockIdx.x * 64;
    const int b = blockIdx.y;
    const float* xb = x_in + b * CR * XSTRIDE;

    // stage weights (transposed: inner index = channel -> conflict-free reads)
    for (int e = tid; e < 2048; e += 256) {
        int c = e >> 6, i2 = e & 63;
        wfT[i2][c] = fw[e];
        wgT[i2][c] = gw[e];
    }
    for (int e = tid; e < 1024; e += 256) {
        int c = e >> 5, i = e & 31;
        rwT[i][c] = rw[e];
    }
    // load x tiles: A = xin(t), B = xin(t+d), with front-pad P of zeros
    {
        int ch = tid >> 3;
        int j0 = (tid & 7) * 8;
        const float* row = xb + ch * XSTRIDE;
#pragma unroll
        for (int k = 0; k < 8; ++k) {
            int t = t0 + j0 + k;
            float a = 0.f, bb = 0.f;
            if (t < T_out) {
                if (t >= P) a = row[t - P];
                bb = row[t + d - P];      // d > P always, so index >= 0
            }
            As[ch][j0 + k] = a;
            Bs[ch][j0 + k] = bb;
        }
    }
    __syncthreads();
    // gated activation
    {
        int c = tid & 31;
        int j0 = (tid >> 5) * 8;
        float af[8] = {0, 0, 0, 0, 0, 0, 0, 0};
        float ag[8] = {0, 0, 0, 0, 0, 0, 0, 0};
#pragma unroll
        for (int i = 0; i < 32; ++i) {
            float av[8], bv[8];
            *(f4*)&av[0] = *(const f4*)&As[i][j0];
            *(f4*)&av[4] = *(const f4*)&As[i][j0 + 4];
            *(f4*)&bv[0] = *(const f4*)&Bs[i][j0];
            *(f4*)&bv[4] = *(const f4*)&Bs[i][j0 + 4];
            float f0 = wfT[2 * i][c], f1 = wfT[2 * i + 1][c];
            float g0 = wgT[2 * i][c], g1 = wgT[2 * i + 1][c];
#pragma unroll
            for (int k = 0; k < 8; ++k) {
                af[k] += f0 * av[k] + f1 * bv[k];
                ag[k] += g0 * av[k] + g1 * bv[k];
            }
        }
#pragma unroll
        for (int k = 0; k < 8; ++k) {
            float e2a = __expf(2.f * af[k]);
            float th = 1.f - __fdividef(2.f, e2a + 1.f);
            float sg = __fdividef(1.f, 1.f + __expf(-ag[k]));
            float z = th * sg;
            Zs[c][j0 + k] = z;
            ZsT[j0 + k][c] = f2bf(z);
        }
    }
    __syncthreads();
    // residual: x_out = Wr z + xin(t+d)
    {
        int ch = tid >> 3;
        int j0 = (tid & 7) * 8;
        float accv[8];
        *(f4*)&accv[0] = *(const f4*)&Bs[ch][j0];
        *(f4*)&accv[4] = *(const f4*)&Bs[ch][j0 + 4];
#pragma unroll
        for (int i = 0; i < 32; ++i) {
            float w = rwT[i][ch];
            float zv[8];
            *(f4*)&zv[0] = *(const f4*)&Zs[i][j0];
            *(f4*)&zv[4] = *(const f4*)&Zs[i][j0 + 4];
#pragma unroll
            for (int k = 0; k < 8; ++k)
                accv[k] += w * zv[k];
        }
        float* orow = x_out + (b * CR + ch) * XSTRIDE;
#pragma unroll
        for (int k = 0; k < 8; ++k) {
            int t = t0 + j0 + k;
            if (t < T_out) orow[t] = accv[k];
        }
    }
    // Zt write-out (channel-contiguous bf16, trailing OUT_T window only)
    {
        int tl = tid >> 2;
        int cq = (tid & 3) * 8;
        int t = t0 + tl;
        if (t >= skipOff && t < T_out) {
            unsigned short* dst =
                Zt + ((size_t)b * OUT_T + (t - skipOff)) * KCAT + kOff + cq;
            *(short8*)dst = *(const short8*)&ZsT[tl][cq];
        }
    }
}

// ---------------- MFMA GEMM: C[b] = A * B[b]^T(+bias)(+relu) ----------------
// A: [M][K] bf16 (K-contig). B: [b][5632][K] bf16 (K-contig rows = N dim).
// MODE 0: out = bf16 [b][5632][M], relu, no bias        (skip stage)
// MODE 1: out = bf16 [b][5632][M], relu, +bias          (post1)
// MODE 2: out = f32  [b][M][5632], +bias, no relu       (post2 / final)
template <int MODE>
__global__ __launch_bounds__(256) void k_gemm(
    const unsigned short* __restrict__ A,
    const unsigned short* __restrict__ B,
    const float* __restrict__ bias,
    void* __restrict__ Cout, int M, int K)
{
    __shared__ unsigned short Asm[128][72];
    __shared__ unsigned short Bsm[64][72];
    const int tid = threadIdx.x;
    const int n0 = blockIdx.x * 64;
    const int m0 = blockIdx.y * 128;
    const int b = blockIdx.z;
    const unsigned short* Bb = B + (size_t)b * OUT_T * K;
    const int lane = tid & 63;
    const int wm = tid >> 6;
    f32x4 acc[2][4];
#pragma unroll
    for (int fm = 0; fm < 2; ++fm)
#pragma unroll
        for (int fn = 0; fn < 4; ++fn)
            acc[fm][fn] = (f32x4){0.f, 0.f, 0.f, 0.f};

    for (int kb = 0; kb < K; kb += 64) {
        __syncthreads();
#pragma unroll
        for (int it = 0; it < 4; ++it) {
            int lin = tid + it * 256;
            int row = lin >> 3, c8 = (lin & 7) * 8;
            *(short8*)&Asm[row][c8] =
                *(const short8*)&A[(size_t)(m0 + row) * K + kb + c8];
        }
#pragma unroll
        for (int it = 0; it < 2; ++it) {
            int lin = tid + it * 256;
            int row = lin >> 3, c8 = (lin & 7) * 8;
            *(short8*)&Bsm[row][c8] =
                *(const short8*)&Bb[(size_t)(n0 + row) * K + kb + c8];
        }
        __syncthreads();
#pragma unroll
        for (int kk = 0; kk < 2; ++kk) {
            short8 a[2], bb[4];
#pragma unroll
            for (int fm = 0; fm < 2; ++fm)
                a[fm] = *(const short8*)&Asm[wm * 32 + fm * 16 + (lane & 15)]
                                           [kk * 32 + (lane >> 4) * 8];
#pragma unroll
            for (int fn = 0; fn < 4; ++fn)
                bb[fn] = *(const short8*)&Bsm[fn * 16 + (lane & 15)]
                                            [kk * 32 + (lane >> 4) * 8];
#pragma unroll
            for (int fm = 0; fm < 2; ++fm)
#pragma unroll
                for (int fn = 0; fn < 4; ++fn)
                    acc[fm][fn] = __builtin_amdgcn_mfma_f32_16x16x32_bf16(
                        a[fm], bb[fn], acc[fm][fn], 0, 0, 0);
        }
    }
    // epilogue
#pragma unroll
    for (int fm = 0; fm < 2; ++fm) {
        int mb = m0 + wm * 32 + fm * 16 + (lane >> 4) * 4;
#pragma unroll
        for (int fn = 0; fn < 4; ++fn) {
            int n = n0 + fn * 16 + (lane & 15);
            float v[4];
#pragma unroll
            for (int r = 0; r < 4; ++r) {
                v[r] = acc[fm][fn][r];
                if (MODE >= 1) v[r] += bias[mb + r];
                if (MODE <= 1) v[r] = v[r] > 0.f ? v[r] : 0.f;
            }
            if (MODE == 2) {
                float* o = (float*)Cout;
#pragma unroll
                for (int r = 0; r < 4; ++r)
                    o[((size_t)b * NV + mb + r) * OUT_T + n] = v[r];
            } else {
                unsigned short* o = (unsigned short*)Cout;
                us4 pk;
#pragma unroll
                for (int r = 0; r < 4; ++r) pk[r] = f2bf(v[r]);
                *(us4*)&o[((size_t)b * OUT_T + n) * M + mb] = pk;
            }
        }
    }
}

extern "C" void kernel_launch(void* const* d_in, const int* in_sizes, int n_in,
                              void* d_out, int out_size, void* d_ws, size_t ws_size,
                              hipStream_t stream)
{
    const int*   tokens  = (const int*)d_in[0];
    const float* emb     = (const float*)d_in[1];
    const float* pre_w   = (const float*)d_in[2];
    const float* filt_w  = (const float*)d_in[3];
    const float* gate_w  = (const float*)d_in[4];
    const float* res_w   = (const float*)d_in[5];
    const float* skip_w  = (const float*)d_in[6];
    const float* post_w1 = (const float*)d_in[7];
    const float* post_b1 = (const float*)d_in[8];
    const float* post_w2 = (const float*)d_in[9];
    const float* post_b2 = (const float*)d_in[10];
    float* out = (float*)d_out;

    char* ws = (char*)d_ws;
    float* xA = (float*)ws;                 ws += (size_t)NB * CR * XSTRIDE * 4;
    float* xB = (float*)ws;                 ws += (size_t)NB * CR * XSTRIDE * 4;
    unsigned short* Zt    = (unsigned short*)ws; ws += (size_t)NB * OUT_T * KCAT * 2;
    unsigned short* skipT = (unsigned short*)ws; ws += (size_t)NB * OUT_T * CS * 2;
    unsigned short* h1T   = (unsigned short*)ws; ws += (size_t)NB * OUT_T * CE * 2;
    unsigned short* wsb   = (unsigned short*)ws; ws += (size_t)CS * KCAT * 2;
    unsigned short* w1b   = (unsigned short*)ws; ws += (size_t)CE * CS * 2;
    unsigned short* w2b   = (unsigned short*)ws; ws += (size_t)NV * CE * 2;

    k_prep<<<3968, 256, 0, stream>>>(skip_w, post_w1, post_w2, wsb, w1b, w2b);
    k_pre<<<(NB * CR * L0) / 256, 256, 0, stream>>>(tokens, emb, pre_w, xA);

    int T = L0;
    int init = 1;
    float* xin = xA;
    float* xout = xB;
    int li = 0;
    for (int blk = 0; blk < 5; ++blk) {
        int nw = 1;
        for (int j = 0; j < 10; ++j) {
            int d = nw;
            int P = 0;
            if (d > init) {
                int r = d / init;
                int l = T / init;
                int nl = ((l + r - 1) / r) * r;
                P = (nl - l) * init;
            }
            int T_out = T + P - d;
            dim3 grid((T_out + 63) / 64, NB);
            k_layer<<<grid, 256, 0, stream>>>(
                xin, xout, Zt,
                filt_w + (size_t)li * CD * CR * 2,
                gate_w + (size_t)li * CD * CR * 2,
                res_w + (size_t)li * CR * CD,
                T_out, d, P, T_out - OUT_T, li * 32);
            float* tmp = xin; xin = xout; xout = tmp;
            T = T_out;
            init = d;
            nw <<= 1;
            ++li;
        }
    }

    dim3 gs(OUT_T / 64, CS / 128, NB);
    k_gemm<0><<<gs, 256, 0, stream>>>(wsb, Zt, nullptr, skipT, CS, KCAT);
    dim3 g1(OUT_T / 64, CE / 128, NB);
    k_gemm<1><<<g1, 256, 0, stream>>>(w1b, skipT, post_b1, h1T, CE, CS);
    dim3 g2(OUT_T / 64, NV / 128, NB);
    k_gemm<2><<<g2, 256, 0, stream>>>(w2b, h1T, post_b2, out, NV, CE);
}